// Round 1
// baseline (4346.523 us; speedup 1.0000x reference)
//
#include <hip/hip_runtime.h>

#define NN 50000
#define NE 800000
#define D  128
#define NC 40

// ---------- edge loading (int32/int64 auto-detect) ----------
__device__ __forceinline__ void load_edge(const void* ei, int e, int is64, int& s, int& d) {
    if (is64) {
        const long long* p = (const long long*)ei;
        s = (int)p[e]; d = (int)p[NE + e];
    } else {
        const int* p = (const int*)ei;
        s = p[e]; d = p[NE + e];
    }
}

// flag=1 if edge_index is int64 (all sampled odd int32 words are zero)
__global__ void detect_kernel(const int* ei, int* flag) {
    __shared__ int nz;
    if (threadIdx.x == 0) nz = 0;
    __syncthreads();
    int c = 0;
    for (int i = threadIdx.x; i < 2048; i += 256)
        if (ei[2 * i + 1] != 0) c = 1;
    if (c) atomicAdd(&nz, 1);
    __syncthreads();
    if (threadIdx.x == 0) *flag = (nz == 0) ? 1 : 0;
}

__global__ void count_deg_kernel(const void* ei, const int* __restrict__ flag, int* deg) {
    int e = blockIdx.x * 256 + threadIdx.x;
    if (e >= NE) return;
    int is64 = *flag;
    int s, d; load_edge(ei, e, is64, s, d);
    if ((unsigned)d < NN) atomicAdd(&deg[d], 1);
}

__global__ void dinv_kernel(const int* __restrict__ deg, float* __restrict__ dinv) {
    int i = blockIdx.x * 256 + threadIdx.x;
    if (i < NN) dinv[i] = 1.0f / sqrtf((float)deg[i] + 1.0f);  // +1 = self-loop
}

// ---------- GEMM: T[M x 128] = A[M x 128] @ W[128 x 128] ----------
// block=256, tile = 32 rows. W fully staged (64KB), A tile XOR-swizzled (16KB).
__global__ __launch_bounds__(256) void gemm128_kernel(const float* __restrict__ A,
                                                      const float* __restrict__ W,
                                                      float* __restrict__ T) {
    __shared__ float sW[D * D];
    __shared__ float sH[32 * D];
    int tid = threadIdx.x;
    const float4* W4 = (const float4*)W;
    float4* sW4 = (float4*)sW;
#pragma unroll
    for (int i = 0; i < 16; ++i) sW4[tid + i * 256] = W4[tid + i * 256];
    int m0 = blockIdx.x * 32;
#pragma unroll
    for (int i = 0; i < 16; ++i) {
        int idx = tid + i * 256;            // 0..4095
        int row = idx >> 7, col = idx & 127;
        int grow = m0 + row;
        float v = (grow < NN) ? A[(size_t)grow * D + col] : 0.0f;
        sH[row * D + (col ^ ((row & 7) << 2))] = v;   // swizzle: conflict-free reads
    }
    __syncthreads();
    int r = tid >> 3, cb = tid & 7;
    int sw = (r & 7) << 2;
    float4 a0 = {0,0,0,0}, a1 = {0,0,0,0}, a2 = {0,0,0,0}, a3 = {0,0,0,0};
#pragma unroll 8
    for (int k = 0; k < D; ++k) {
        float a = sH[r * D + (k ^ sw)];
        const float4* wr = (const float4*)&sW[k * D];
        float4 w0 = wr[cb], w1 = wr[cb + 8], w2 = wr[cb + 16], w3 = wr[cb + 24];
        a0.x = fmaf(a, w0.x, a0.x); a0.y = fmaf(a, w0.y, a0.y);
        a0.z = fmaf(a, w0.z, a0.z); a0.w = fmaf(a, w0.w, a0.w);
        a1.x = fmaf(a, w1.x, a1.x); a1.y = fmaf(a, w1.y, a1.y);
        a1.z = fmaf(a, w1.z, a1.z); a1.w = fmaf(a, w1.w, a1.w);
        a2.x = fmaf(a, w2.x, a2.x); a2.y = fmaf(a, w2.y, a2.y);
        a2.z = fmaf(a, w2.z, a2.z); a2.w = fmaf(a, w2.w, a2.w);
        a3.x = fmaf(a, w3.x, a3.x); a3.y = fmaf(a, w3.y, a3.y);
        a3.z = fmaf(a, w3.z, a3.z); a3.w = fmaf(a, w3.w, a3.w);
    }
    int grow = m0 + r;
    if (grow < NN) {
        float4* O = (float4*)(T + (size_t)grow * D);
        O[cb] = a0; O[cb + 8] = a1; O[cb + 16] = a2; O[cb + 24] = a3;
    }
}

// acc = t * dinv[row]^2   (self-loop contribution initializes the accumulator)
__global__ void init_acc_kernel(const float* __restrict__ T, const float* __restrict__ dinv,
                                float* __restrict__ acc) {
    int i = blockIdx.x * 256 + threadIdx.x;     // float4 index
    if (i >= NN * 32) return;
    int row = i >> 5;
    float w = dinv[row]; w *= w;
    float4 v = ((const float4*)T)[i];
    v.x *= w; v.y *= w; v.z *= w; v.w *= w;
    ((float4*)acc)[i] = v;
}

// 32 lanes per edge, 4 floats each: acc[dst] += t[src] * dinv[s]*dinv[d]
__global__ __launch_bounds__(256) void scatter_kernel(const float* __restrict__ T,
                                                      const void* ei,
                                                      const int* __restrict__ flag,
                                                      const float* __restrict__ dinv,
                                                      float* __restrict__ acc) {
    long long g = (long long)blockIdx.x * 256 + threadIdx.x;
    int e = (int)(g >> 5);
    int lane = (int)(g & 31);
    if (e >= NE) return;
    int is64 = *flag;
    int s, d; load_edge(ei, e, is64, s, d);
    if ((unsigned)s >= NN || (unsigned)d >= NN) return;
    float w = dinv[s] * dinv[d];
    float4 v = ((const float4*)(T + (size_t)s * D))[lane];
    float* a = acc + (size_t)d * D + lane * 4;
    atomicAdd(a + 0, v.x * w);
    atomicAdd(a + 1, v.y * w);
    atomicAdd(a + 2, v.z * w);
    atomicAdd(a + 3, v.w * w);
}

__global__ void bias_relu_kernel(const float* __restrict__ acc, const float* __restrict__ b,
                                 float* __restrict__ out) {
    int i = blockIdx.x * 256 + threadIdx.x;     // float4 index
    if (i >= NN * 32) return;
    float4 v = ((const float4*)acc)[i];
    float4 bb = ((const float4*)b)[i & 31];
    v.x = fmaxf(v.x + bb.x, 0.0f);
    v.y = fmaxf(v.y + bb.y, 0.0f);
    v.z = fmaxf(v.z + bb.z, 0.0f);
    v.w = fmaxf(v.w + bb.w, 0.0f);
    ((float4*)out)[i] = v;
}

// O[M x 40] = A[M x 128] @ W[128 x 40] + b
__global__ __launch_bounds__(256) void fc_kernel(const float* __restrict__ A,
                                                 const float* __restrict__ W,
                                                 const float* __restrict__ b,
                                                 float* __restrict__ O) {
    __shared__ float sW[D * NC];
    __shared__ float sH[64 * D];
    int tid = threadIdx.x;
    for (int i = tid; i < D * NC; i += 256) sW[i] = W[i];
    int m0 = blockIdx.x * 64;
#pragma unroll
    for (int i = 0; i < 32; ++i) {
        int idx = tid + i * 256;
        int row = idx >> 7, col = idx & 127;
        int grow = m0 + row;
        float v = (grow < NN) ? A[(size_t)grow * D + col] : 0.0f;
        sH[row * D + (col ^ ((row & 7) << 2))] = v;
    }
    __syncthreads();
    int r = tid >> 2, c0 = (tid & 3) * 10;
    int sw = (r & 7) << 2;
    float acc[10];
#pragma unroll
    for (int j = 0; j < 10; ++j) acc[j] = 0.0f;
    for (int k = 0; k < D; ++k) {
        float a = sH[r * D + (k ^ sw)];
#pragma unroll
        for (int j = 0; j < 10; ++j) acc[j] = fmaf(a, sW[k * NC + c0 + j], acc[j]);
    }
    int grow = m0 + r;
    if (grow < NN) {
#pragma unroll
        for (int j = 0; j < 10; ++j) O[(size_t)grow * NC + c0 + j] = acc[j] + b[c0 + j];
    }
}

extern "C" void kernel_launch(void* const* d_in, const int* in_sizes, int n_in,
                              void* d_out, int out_size, void* d_ws, size_t ws_size,
                              hipStream_t stream) {
    const float* x   = (const float*)d_in[0];
    const void*  ei  = d_in[1];
    const float* W1  = (const float*)d_in[2];
    const float* b1  = (const float*)d_in[3];
    const float* W2  = (const float*)d_in[4];
    const float* b2  = (const float*)d_in[5];
    const float* W3  = (const float*)d_in[6];
    const float* b3  = (const float*)d_in[7];
    const float* fcW = (const float*)d_in[8];
    const float* fcb = (const float*)d_in[9];

    float* out_h  = (float*)d_out;                       // [NN x 128]
    float* out_fc = out_h + (size_t)NN * D;              // [NN x 40]

    size_t off = 0;
    auto alloc = [&](size_t bytes) {
        void* p = (char*)d_ws + off;
        off += (bytes + 255) & ~(size_t)255;
        return p;
    };
    float* dinv   = (float*)alloc((size_t)NN * 4);
    int*   deg    = (int*)  alloc((size_t)NN * 4);
    int*   flag   = (int*)  alloc(256);
    float* bufT   = (float*)alloc((size_t)NN * D * 4);
    float* bufAcc = (float*)alloc((size_t)NN * D * 4);
    float* bufH   = (float*)alloc((size_t)NN * D * 4);
    (void)ws_size; (void)in_sizes; (void)n_in; (void)out_size;

    hipMemsetAsync(deg, 0, (size_t)NN * 4, stream);
    detect_kernel<<<1, 256, 0, stream>>>((const int*)ei, flag);
    count_deg_kernel<<<(NE + 255) / 256, 256, 0, stream>>>(ei, flag, deg);
    dinv_kernel<<<(NN + 255) / 256, 256, 0, stream>>>(deg, dinv);

    auto layer = [&](const float* in, const float* W, const float* b, float* t, float* out) {
        gemm128_kernel<<<(NN + 31) / 32, 256, 0, stream>>>(in, W, t);
        init_acc_kernel<<<(NN * 32 + 255) / 256, 256, 0, stream>>>(t, dinv, bufAcc);
        scatter_kernel<<<(int)(((long long)NE * 32 + 255) / 256), 256, 0, stream>>>(t, ei, flag, dinv, bufAcc);
        bias_relu_kernel<<<(NN * 32 + 255) / 256, 256, 0, stream>>>(bufAcc, b, out);
    };

    layer(x,    W1, b1, bufT, bufH);
    layer(bufH, W2, b2, bufT, bufT);   // out may alias t: t is dead after scatter
    layer(bufT, W3, b3, bufH, out_h);

    fc_kernel<<<(NN + 63) / 64, 256, 0, stream>>>(out_h, fcW, fcb, out_fc);
}

// Round 2
// 552.737 us; speedup vs baseline: 7.8636x; 7.8636x over previous
//
#include <hip/hip_runtime.h>

#define NN 50000
#define NE 800000
#define D  128
#define NC 40

// ---------- edge loading (int32/int64 auto-detect) ----------
__device__ __forceinline__ void load_edge(const void* ei, int e, int is64, int& s, int& d) {
    if (is64) {
        const long long* p = (const long long*)ei;
        s = (int)p[e]; d = (int)p[NE + e];
    } else {
        const int* p = (const int*)ei;
        s = p[e]; d = p[NE + e];
    }
}

// flag=1 if edge_index is int64 (all sampled odd int32 words are zero)
__global__ void detect_kernel(const int* ei, int* flag) {
    __shared__ int nz;
    if (threadIdx.x == 0) nz = 0;
    __syncthreads();
    int c = 0;
    for (int i = threadIdx.x; i < 2048; i += 256)
        if (ei[2 * i + 1] != 0) c = 1;
    if (c) atomicAdd(&nz, 1);
    __syncthreads();
    if (threadIdx.x == 0) *flag = (nz == 0) ? 1 : 0;
}

__global__ void count_deg_kernel(const void* ei, const int* __restrict__ flag, int* deg) {
    int e = blockIdx.x * 256 + threadIdx.x;
    if (e >= NE) return;
    int is64 = *flag;
    int s, d; load_edge(ei, e, is64, s, d);
    if ((unsigned)d < NN) atomicAdd(&deg[d], 1);
}

__global__ void dinv_kernel(const int* __restrict__ deg, float* __restrict__ dinv) {
    int i = blockIdx.x * 256 + threadIdx.x;
    if (i < NN) dinv[i] = 1.0f / sqrtf((float)deg[i] + 1.0f);  // +1 = self-loop
}

// single-block exclusive scan: rowptr[0..NN] from deg[0..NN-1]
__global__ __launch_bounds__(1024) void scan_kernel(const int* __restrict__ deg,
                                                    int* __restrict__ rowptr) {
    __shared__ int part[1024];
    int t = threadIdx.x;
    const int CH = (NN + 1023) / 1024;      // 49
    int beg = t * CH;
    int end = beg + CH; if (end > NN) end = NN;
    int s = 0;
    for (int i = beg; i < end; ++i) s += deg[i];
    part[t] = s;
    __syncthreads();
    for (int off = 1; off < 1024; off <<= 1) {
        int v = (t >= off) ? part[t - off] : 0;
        __syncthreads();
        part[t] += v;
        __syncthreads();
    }
    int ex = (t == 0) ? 0 : part[t - 1];
    for (int i = beg; i < end; ++i) {
        rowptr[i] = ex;
        ex += deg[i];
    }
    if (t == 1023) rowptr[NN] = ex;
}

// scatter edge ids into CSR slots; weight precomputed
__global__ void fill_kernel(const void* ei, const int* __restrict__ flag,
                            const int* __restrict__ rowptr, int* cursor,
                            const float* __restrict__ dinv,
                            int* __restrict__ srcs, float* __restrict__ wts) {
    int e = blockIdx.x * 256 + threadIdx.x;
    if (e >= NE) return;
    int is64 = *flag;
    int s, d; load_edge(ei, e, is64, s, d);
    if ((unsigned)s >= NN || (unsigned)d >= NN) return;
    int slot = rowptr[d] + atomicAdd(&cursor[d], 1);
    srcs[slot] = s;
    wts[slot] = dinv[s] * dinv[d];
}

// ---------- GEMM: T[M x 128] = A[M x 128] @ W[128 x 128] ----------
__global__ __launch_bounds__(256) void gemm128_kernel(const float* __restrict__ A,
                                                      const float* __restrict__ W,
                                                      float* __restrict__ T) {
    __shared__ float sW[D * D];
    __shared__ float sH[32 * D];
    int tid = threadIdx.x;
    const float4* W4 = (const float4*)W;
    float4* sW4 = (float4*)sW;
#pragma unroll
    for (int i = 0; i < 16; ++i) sW4[tid + i * 256] = W4[tid + i * 256];
    int m0 = blockIdx.x * 32;
#pragma unroll
    for (int i = 0; i < 16; ++i) {
        int idx = tid + i * 256;            // 0..4095
        int row = idx >> 7, col = idx & 127;
        int grow = m0 + row;
        float v = (grow < NN) ? A[(size_t)grow * D + col] : 0.0f;
        sH[row * D + (col ^ ((row & 7) << 2))] = v;   // swizzle: conflict-free reads
    }
    __syncthreads();
    int r = tid >> 3, cb = tid & 7;
    int sw = (r & 7) << 2;
    float4 a0 = {0,0,0,0}, a1 = {0,0,0,0}, a2 = {0,0,0,0}, a3 = {0,0,0,0};
#pragma unroll 8
    for (int k = 0; k < D; ++k) {
        float a = sH[r * D + (k ^ sw)];
        const float4* wr = (const float4*)&sW[k * D];
        float4 w0 = wr[cb], w1 = wr[cb + 8], w2 = wr[cb + 16], w3 = wr[cb + 24];
        a0.x = fmaf(a, w0.x, a0.x); a0.y = fmaf(a, w0.y, a0.y);
        a0.z = fmaf(a, w0.z, a0.z); a0.w = fmaf(a, w0.w, a0.w);
        a1.x = fmaf(a, w1.x, a1.x); a1.y = fmaf(a, w1.y, a1.y);
        a1.z = fmaf(a, w1.z, a1.z); a1.w = fmaf(a, w1.w, a1.w);
        a2.x = fmaf(a, w2.x, a2.x); a2.y = fmaf(a, w2.y, a2.y);
        a2.z = fmaf(a, w2.z, a2.z); a2.w = fmaf(a, w2.w, a2.w);
        a3.x = fmaf(a, w3.x, a3.x); a3.y = fmaf(a, w3.y, a3.y);
        a3.z = fmaf(a, w3.z, a3.z); a3.w = fmaf(a, w3.w, a3.w);
    }
    int grow = m0 + r;
    if (grow < NN) {
        float4* O = (float4*)(T + (size_t)grow * D);
        O[cb] = a0; O[cb + 8] = a1; O[cb + 16] = a2; O[cb + 24] = a3;
    }
}

// ---------- CSR pull: out[d] = relu( sum_in(T[s]*w) + T[d]*dinv^2 + b ) ----------
// one 64-lane wave per dst node, float2 per lane
__global__ __launch_bounds__(256) void aggregate_kernel(const float* __restrict__ T,
                                                        const int* __restrict__ rowptr,
                                                        const int* __restrict__ srcs,
                                                        const float* __restrict__ wts,
                                                        const float* __restrict__ dinv,
                                                        const float* __restrict__ b,
                                                        float* __restrict__ out) {
    int wid = (blockIdx.x * 256 + threadIdx.x) >> 6;
    int lane = threadIdx.x & 63;
    if (wid >= NN) return;
    float di = dinv[wid];
    float wself = di * di;
    float2 acc = ((const float2*)(T + (size_t)wid * D))[lane];
    acc.x *= wself; acc.y *= wself;
    int beg = rowptr[wid], end = rowptr[wid + 1];
    int e = beg;
    for (; e + 1 < end; e += 2) {
        int s0 = srcs[e], s1 = srcs[e + 1];
        float wa = wts[e], wb = wts[e + 1];
        float2 v0 = ((const float2*)(T + (size_t)s0 * D))[lane];
        float2 v1 = ((const float2*)(T + (size_t)s1 * D))[lane];
        acc.x = fmaf(v0.x, wa, acc.x); acc.y = fmaf(v0.y, wa, acc.y);
        acc.x = fmaf(v1.x, wb, acc.x); acc.y = fmaf(v1.y, wb, acc.y);
    }
    if (e < end) {
        int s0 = srcs[e];
        float wa = wts[e];
        float2 v0 = ((const float2*)(T + (size_t)s0 * D))[lane];
        acc.x = fmaf(v0.x, wa, acc.x); acc.y = fmaf(v0.y, wa, acc.y);
    }
    float2 bb = ((const float2*)b)[lane];
    acc.x = fmaxf(acc.x + bb.x, 0.0f);
    acc.y = fmaxf(acc.y + bb.y, 0.0f);
    ((float2*)(out + (size_t)wid * D))[lane] = acc;
}

// O[M x 40] = A[M x 128] @ W[128 x 40] + b
__global__ __launch_bounds__(256) void fc_kernel(const float* __restrict__ A,
                                                 const float* __restrict__ W,
                                                 const float* __restrict__ b,
                                                 float* __restrict__ O) {
    __shared__ float sW[D * NC];
    __shared__ float sH[64 * D];
    int tid = threadIdx.x;
    for (int i = tid; i < D * NC; i += 256) sW[i] = W[i];
    int m0 = blockIdx.x * 64;
#pragma unroll
    for (int i = 0; i < 32; ++i) {
        int idx = tid + i * 256;
        int row = idx >> 7, col = idx & 127;
        int grow = m0 + row;
        float v = (grow < NN) ? A[(size_t)grow * D + col] : 0.0f;
        sH[row * D + (col ^ ((row & 7) << 2))] = v;
    }
    __syncthreads();
    int r = tid >> 2, c0 = (tid & 3) * 10;
    int sw = (r & 7) << 2;
    float acc[10];
#pragma unroll
    for (int j = 0; j < 10; ++j) acc[j] = 0.0f;
    for (int k = 0; k < D; ++k) {
        float a = sH[r * D + (k ^ sw)];
#pragma unroll
        for (int j = 0; j < 10; ++j) acc[j] = fmaf(a, sW[k * NC + c0 + j], acc[j]);
    }
    int grow = m0 + r;
    if (grow < NN) {
#pragma unroll
        for (int j = 0; j < 10; ++j) O[(size_t)grow * NC + c0 + j] = acc[j] + b[c0 + j];
    }
}

extern "C" void kernel_launch(void* const* d_in, const int* in_sizes, int n_in,
                              void* d_out, int out_size, void* d_ws, size_t ws_size,
                              hipStream_t stream) {
    const float* x   = (const float*)d_in[0];
    const void*  ei  = d_in[1];
    const float* W1  = (const float*)d_in[2];
    const float* b1  = (const float*)d_in[3];
    const float* W2  = (const float*)d_in[4];
    const float* b2  = (const float*)d_in[5];
    const float* W3  = (const float*)d_in[6];
    const float* b3  = (const float*)d_in[7];
    const float* fcW = (const float*)d_in[8];
    const float* fcb = (const float*)d_in[9];

    float* out_h  = (float*)d_out;                       // [NN x 128]
    float* out_fc = out_h + (size_t)NN * D;              // [NN x 40]

    size_t off = 0;
    auto alloc = [&](size_t bytes) {
        void* p = (char*)d_ws + off;
        off += (bytes + 255) & ~(size_t)255;
        return p;
    };
    float* dinv   = (float*)alloc((size_t)NN * 4);
    int*   deg    = (int*)  alloc((size_t)NN * 4);
    int*   flag   = (int*)  alloc(256);
    int*   rowptr = (int*)  alloc((size_t)(NN + 1) * 4);
    int*   cursor = (int*)  alloc((size_t)NN * 4);
    int*   srcs   = (int*)  alloc((size_t)NE * 4);
    float* wts    = (float*)alloc((size_t)NE * 4);
    float* bufT   = (float*)alloc((size_t)NN * D * 4);
    float* bufH   = (float*)alloc((size_t)NN * D * 4);
    (void)ws_size; (void)in_sizes; (void)n_in; (void)out_size;

    hipMemsetAsync(deg, 0, (size_t)NN * 4, stream);
    hipMemsetAsync(cursor, 0, (size_t)NN * 4, stream);
    detect_kernel<<<1, 256, 0, stream>>>((const int*)ei, flag);
    count_deg_kernel<<<(NE + 255) / 256, 256, 0, stream>>>(ei, flag, deg);
    dinv_kernel<<<(NN + 255) / 256, 256, 0, stream>>>(deg, dinv);
    scan_kernel<<<1, 1024, 0, stream>>>(deg, rowptr);
    fill_kernel<<<(NE + 255) / 256, 256, 0, stream>>>(ei, flag, rowptr, cursor, dinv, srcs, wts);

    auto layer = [&](const float* in, const float* W, const float* b, float* out) {
        gemm128_kernel<<<(NN + 31) / 32, 256, 0, stream>>>(in, W, bufT);
        aggregate_kernel<<<(NN * 64 + 255) / 256, 256, 0, stream>>>(bufT, rowptr, srcs, wts, dinv, b, out);
    };

    layer(x,    W1, b1, bufH);
    layer(bufH, W2, b2, bufH);   // aggregate reads only bufT; overwrite of bufH is safe
    layer(bufH, W3, b3, out_h);

    fc_kernel<<<(NN + 63) / 64, 256, 0, stream>>>(out_h, fcW, fcb, out_fc);
}

// Round 3
// 404.948 us; speedup vs baseline: 10.7335x; 1.3650x over previous
//
#include <hip/hip_runtime.h>

#define NN 50000
#define NE 800000
#define D  128
#define NC 40
#define NBLK ((NN + 255) / 256)   // 196 scan blocks

// ---------- edge loading (int32/int64 auto-detect) ----------
__device__ __forceinline__ void load_edge(const void* ei, int e, int is64, int& s, int& d) {
    if (is64) {
        const long long* p = (const long long*)ei;
        s = (int)p[e]; d = (int)p[NE + e];
    } else {
        const int* p = (const int*)ei;
        s = p[e]; d = p[NE + e];
    }
}

// flag=1 if edge_index is int64 (all sampled odd int32 words are zero)
__global__ void detect_kernel(const int* ei, int* flag) {
    __shared__ int nz;
    if (threadIdx.x == 0) nz = 0;
    __syncthreads();
    int c = 0;
    for (int i = threadIdx.x; i < 2048; i += 256)
        if (ei[2 * i + 1] != 0) c = 1;
    if (c) atomicAdd(&nz, 1);
    __syncthreads();
    if (threadIdx.x == 0) *flag = (nz == 0) ? 1 : 0;
}

__global__ void count_deg_kernel(const void* ei, const int* __restrict__ flag, int* deg) {
    int e = blockIdx.x * 256 + threadIdx.x;
    if (e >= NE) return;
    int is64 = *flag;
    int s, d; load_edge(ei, e, is64, s, d);
    if ((unsigned)d < NN) atomicAdd(&deg[d], 1);
}

// ---------- multi-block exclusive scan of deg -> rowptr (+ dinv fused) ----------
__global__ __launch_bounds__(256) void scan_part_kernel(const int* __restrict__ deg,
                                                        int* __restrict__ part) {
    __shared__ int s[256];
    int t = threadIdx.x, i = blockIdx.x * 256 + t;
    s[t] = (i < NN) ? deg[i] : 0;
    __syncthreads();
    for (int off = 128; off > 0; off >>= 1) {
        if (t < off) s[t] += s[t + off];
        __syncthreads();
    }
    if (t == 0) part[blockIdx.x] = s[0];
}

__global__ __launch_bounds__(256) void scan_mid_kernel(int* __restrict__ part,
                                                       int* __restrict__ rowptr) {
    __shared__ int s[256];
    int t = threadIdx.x;
    int v = (t < NBLK) ? part[t] : 0;
    s[t] = v;
    __syncthreads();
    for (int off = 1; off < 256; off <<= 1) {
        int u = (t >= off) ? s[t - off] : 0;
        __syncthreads();
        s[t] += u;
        __syncthreads();
    }
    if (t < NBLK) part[t] = s[t] - v;        // exclusive block offsets
    if (t == 255) rowptr[NN] = s[255];       // total edge count
}

__global__ __launch_bounds__(256) void scan_write_kernel(const int* __restrict__ deg,
                                                         const int* __restrict__ part,
                                                         int* __restrict__ rowptr,
                                                         float* __restrict__ dinv) {
    __shared__ int s[256];
    int t = threadIdx.x, i = blockIdx.x * 256 + t;
    int v = (i < NN) ? deg[i] : 0;
    s[t] = v;
    __syncthreads();
    for (int off = 1; off < 256; off <<= 1) {
        int u = (t >= off) ? s[t - off] : 0;
        __syncthreads();
        s[t] += u;
        __syncthreads();
    }
    if (i < NN) {
        rowptr[i] = part[blockIdx.x] + s[t] - v;
        dinv[i] = 1.0f / sqrtf((float)v + 1.0f);   // +1 = self-loop
    }
}

// scatter edge ids into CSR slots; weight precomputed
__global__ void fill_kernel(const void* ei, const int* __restrict__ flag,
                            const int* __restrict__ rowptr, int* cursor,
                            const float* __restrict__ dinv,
                            int* __restrict__ srcs, float* __restrict__ wts) {
    int e = blockIdx.x * 256 + threadIdx.x;
    if (e >= NE) return;
    int is64 = *flag;
    int s, d; load_edge(ei, e, is64, s, d);
    if ((unsigned)s >= NN || (unsigned)d >= NN) return;
    int slot = rowptr[d] + atomicAdd(&cursor[d], 1);
    srcs[slot] = s;
    wts[slot] = dinv[s] * dinv[d];
}

// ---------- GEMM: T[M x 128] = A[M x 128] @ W[128 x 128] ----------
// 64-row tile, K chunked by 64. Thread = 4 rows x 8 cols (cols tx*4 and tx*4+64).
// Per k: 4 conflict-free b32 A-reads (pad-65 rows) + 2 contiguous b128 W-reads,
// 32 FMAs -> VALU-bound. LDS 48.6 KB -> 3 blocks/CU.
__global__ __launch_bounds__(256) void gemm128_kernel(const float* __restrict__ A,
                                                      const float* __restrict__ W,
                                                      float* __restrict__ T) {
    __shared__ float sW[64 * D];      // 32 KB: W rows k0..k0+63
    __shared__ float sA[64 * 65];     // 16.6 KB: A tile cols k0..k0+63, pad 65
    int tid = threadIdx.x;
    int ty = tid >> 4, tx = tid & 15;
    int r0 = ty * 4;
    int m0 = blockIdx.x * 64;
    float4 acc[4][2];
#pragma unroll
    for (int j = 0; j < 4; ++j) {
        acc[j][0] = make_float4(0, 0, 0, 0);
        acc[j][1] = make_float4(0, 0, 0, 0);
    }
    float4* sW4 = (float4*)sW;
    for (int k0 = 0; k0 < D; k0 += 64) {
        const float4* W4 = (const float4*)(W + (size_t)k0 * D);
#pragma unroll
        for (int i = 0; i < 8; ++i) sW4[tid + i * 256] = W4[tid + i * 256];
#pragma unroll
        for (int i = 0; i < 4; ++i) {
            int idx = tid + i * 256;      // 0..1023
            int row = idx >> 4;           // 0..63
            int c4 = idx & 15;
            int grow = m0 + row;
            float4 v = make_float4(0, 0, 0, 0);
            if (grow < NN) v = *(const float4*)(A + (size_t)grow * D + k0 + c4 * 4);
            float* dst = &sA[row * 65 + c4 * 4];
            dst[0] = v.x; dst[1] = v.y; dst[2] = v.z; dst[3] = v.w;
        }
        __syncthreads();
#pragma unroll 4
        for (int kk = 0; kk < 64; ++kk) {
            float4 w0 = sW4[kk * 32 + tx];
            float4 w1 = sW4[kk * 32 + tx + 16];
#pragma unroll
            for (int j = 0; j < 4; ++j) {
                float a = sA[(r0 + j) * 65 + kk];
                acc[j][0].x = fmaf(a, w0.x, acc[j][0].x);
                acc[j][0].y = fmaf(a, w0.y, acc[j][0].y);
                acc[j][0].z = fmaf(a, w0.z, acc[j][0].z);
                acc[j][0].w = fmaf(a, w0.w, acc[j][0].w);
                acc[j][1].x = fmaf(a, w1.x, acc[j][1].x);
                acc[j][1].y = fmaf(a, w1.y, acc[j][1].y);
                acc[j][1].z = fmaf(a, w1.z, acc[j][1].z);
                acc[j][1].w = fmaf(a, w1.w, acc[j][1].w);
            }
        }
        __syncthreads();
    }
#pragma unroll
    for (int j = 0; j < 4; ++j) {
        int grow = m0 + r0 + j;
        if (grow < NN) {
            float4* O = (float4*)(T + (size_t)grow * D);
            O[tx] = acc[j][0];
            O[tx + 16] = acc[j][1];
        }
    }
}

// ---------- CSR pull: out[d] = relu( sum_in(T[s]*w) + T[d]*dinv^2 + b ) ----------
// one 64-lane wave per dst node, float2 per lane, 4-edge unroll for MLP
__global__ __launch_bounds__(256) void aggregate_kernel(const float* __restrict__ T,
                                                        const int* __restrict__ rowptr,
                                                        const int* __restrict__ srcs,
                                                        const float* __restrict__ wts,
                                                        const float* __restrict__ dinv,
                                                        const float* __restrict__ b,
                                                        float* __restrict__ out) {
    int wid = (blockIdx.x * 256 + threadIdx.x) >> 6;
    int lane = threadIdx.x & 63;
    if (wid >= NN) return;
    float di = dinv[wid];
    float wself = di * di;
    float2 acc = ((const float2*)(T + (size_t)wid * D))[lane];
    acc.x *= wself; acc.y *= wself;
    int beg = rowptr[wid], end = rowptr[wid + 1];
    int e = beg;
    for (; e + 3 < end; e += 4) {
        int s0 = srcs[e], s1 = srcs[e + 1], s2 = srcs[e + 2], s3 = srcs[e + 3];
        float w0 = wts[e], w1 = wts[e + 1], w2 = wts[e + 2], w3 = wts[e + 3];
        float2 v0 = ((const float2*)(T + (size_t)s0 * D))[lane];
        float2 v1 = ((const float2*)(T + (size_t)s1 * D))[lane];
        float2 v2 = ((const float2*)(T + (size_t)s2 * D))[lane];
        float2 v3 = ((const float2*)(T + (size_t)s3 * D))[lane];
        acc.x = fmaf(v0.x, w0, acc.x); acc.y = fmaf(v0.y, w0, acc.y);
        acc.x = fmaf(v1.x, w1, acc.x); acc.y = fmaf(v1.y, w1, acc.y);
        acc.x = fmaf(v2.x, w2, acc.x); acc.y = fmaf(v2.y, w2, acc.y);
        acc.x = fmaf(v3.x, w3, acc.x); acc.y = fmaf(v3.y, w3, acc.y);
    }
    for (; e < end; ++e) {
        int s0 = srcs[e];
        float w0 = wts[e];
        float2 v0 = ((const float2*)(T + (size_t)s0 * D))[lane];
        acc.x = fmaf(v0.x, w0, acc.x); acc.y = fmaf(v0.y, w0, acc.y);
    }
    float2 bb = ((const float2*)b)[lane];
    acc.x = fmaxf(acc.x + bb.x, 0.0f);
    acc.y = fmaxf(acc.y + bb.y, 0.0f);
    ((float2*)(out + (size_t)wid * D))[lane] = acc;
}

// O[M x 40] = A[M x 128] @ W[128 x 40] + b
__global__ __launch_bounds__(256) void fc_kernel(const float* __restrict__ A,
                                                 const float* __restrict__ W,
                                                 const float* __restrict__ b,
                                                 float* __restrict__ O) {
    __shared__ float sW[D * NC];
    __shared__ float sH[64 * D];
    int tid = threadIdx.x;
    for (int i = tid; i < D * NC; i += 256) sW[i] = W[i];
    int m0 = blockIdx.x * 64;
#pragma unroll
    for (int i = 0; i < 32; ++i) {
        int idx = tid + i * 256;
        int row = idx >> 7, col = idx & 127;
        int grow = m0 + row;
        float v = (grow < NN) ? A[(size_t)grow * D + col] : 0.0f;
        sH[row * D + (col ^ ((row & 7) << 2))] = v;
    }
    __syncthreads();
    int r = tid >> 2, c0 = (tid & 3) * 10;
    int sw = (r & 7) << 2;
    float acc[10];
#pragma unroll
    for (int j = 0; j < 10; ++j) acc[j] = 0.0f;
    for (int k = 0; k < D; ++k) {
        float a = sH[r * D + (k ^ sw)];
#pragma unroll
        for (int j = 0; j < 10; ++j) acc[j] = fmaf(a, sW[k * NC + c0 + j], acc[j]);
    }
    int grow = m0 + r;
    if (grow < NN) {
#pragma unroll
        for (int j = 0; j < 10; ++j) O[(size_t)grow * NC + c0 + j] = acc[j] + b[c0 + j];
    }
}

extern "C" void kernel_launch(void* const* d_in, const int* in_sizes, int n_in,
                              void* d_out, int out_size, void* d_ws, size_t ws_size,
                              hipStream_t stream) {
    const float* x   = (const float*)d_in[0];
    const void*  ei  = d_in[1];
    const float* W1  = (const float*)d_in[2];
    const float* b1  = (const float*)d_in[3];
    const float* W2  = (const float*)d_in[4];
    const float* b2  = (const float*)d_in[5];
    const float* W3  = (const float*)d_in[6];
    const float* b3  = (const float*)d_in[7];
    const float* fcW = (const float*)d_in[8];
    const float* fcb = (const float*)d_in[9];

    float* out_h  = (float*)d_out;                       // [NN x 128]
    float* out_fc = out_h + (size_t)NN * D;              // [NN x 40]

    size_t off = 0;
    auto alloc = [&](size_t bytes) {
        void* p = (char*)d_ws + off;
        off += (bytes + 255) & ~(size_t)255;
        return p;
    };
    float* dinv   = (float*)alloc((size_t)NN * 4);
    int*   deg    = (int*)  alloc((size_t)NN * 4);
    int*   flag   = (int*)  alloc(256);
    int*   part   = (int*)  alloc((size_t)NBLK * 4);
    int*   rowptr = (int*)  alloc((size_t)(NN + 1) * 4);
    int*   cursor = (int*)  alloc((size_t)NN * 4);
    int*   srcs   = (int*)  alloc((size_t)NE * 4);
    float* wts    = (float*)alloc((size_t)NE * 4);
    float* bufT   = (float*)alloc((size_t)NN * D * 4);
    float* bufH   = (float*)alloc((size_t)NN * D * 4);
    (void)ws_size; (void)in_sizes; (void)n_in; (void)out_size;

    hipMemsetAsync(deg, 0, (size_t)NN * 4, stream);
    hipMemsetAsync(cursor, 0, (size_t)NN * 4, stream);
    detect_kernel<<<1, 256, 0, stream>>>((const int*)ei, flag);
    count_deg_kernel<<<(NE + 255) / 256, 256, 0, stream>>>(ei, flag, deg);
    scan_part_kernel<<<NBLK, 256, 0, stream>>>(deg, part);
    scan_mid_kernel<<<1, 256, 0, stream>>>(part, rowptr);
    scan_write_kernel<<<NBLK, 256, 0, stream>>>(deg, part, rowptr, dinv);
    fill_kernel<<<(NE + 255) / 256, 256, 0, stream>>>(ei, flag, rowptr, cursor, dinv, srcs, wts);

    auto layer = [&](const float* in, const float* W, const float* b, float* out) {
        gemm128_kernel<<<(NN + 63) / 64, 256, 0, stream>>>(in, W, bufT);
        aggregate_kernel<<<(NN * 64 + 255) / 256, 256, 0, stream>>>(bufT, rowptr, srcs, wts, dinv, b, out);
    };

    layer(x,    W1, b1, bufH);
    layer(bufH, W2, b2, bufH);   // aggregate reads only bufT; overwrite of bufH is safe
    layer(bufH, W3, b3, out_h);

    fc_kernel<<<(NN + 63) / 64, 256, 0, stream>>>(out_h, fcW, fcb, out_fc);
}

// Round 4
// 396.376 us; speedup vs baseline: 10.9657x; 1.0216x over previous
//
#include <hip/hip_runtime.h>

#define NN 50000
#define NE 800000
#define D  128
#define NC 40
#define NBLK ((NN + 255) / 256)   // 196 scan blocks

// ---------- edge loading (int32/int64 auto-detect) ----------
__device__ __forceinline__ void load_edge(const void* ei, int e, int is64, int& s, int& d) {
    if (is64) {
        const long long* p = (const long long*)ei;
        s = (int)p[e]; d = (int)p[NE + e];
    } else {
        const int* p = (const int*)ei;
        s = p[e]; d = p[NE + e];
    }
}

// flag=1 if edge_index is int64 (all sampled odd int32 words are zero)
__global__ void detect_kernel(const int* ei, int* flag) {
    __shared__ int nz;
    if (threadIdx.x == 0) nz = 0;
    __syncthreads();
    int c = 0;
    for (int i = threadIdx.x; i < 2048; i += 256)
        if (ei[2 * i + 1] != 0) c = 1;
    if (c) atomicAdd(&nz, 1);
    __syncthreads();
    if (threadIdx.x == 0) *flag = (nz == 0) ? 1 : 0;
}

__global__ void count_deg_kernel(const void* ei, const int* __restrict__ flag, int* deg) {
    int e = blockIdx.x * 256 + threadIdx.x;
    if (e >= NE) return;
    int is64 = *flag;
    int s, d; load_edge(ei, e, is64, s, d);
    if ((unsigned)d < NN) atomicAdd(&deg[d], 1);
}

// ---------- multi-block exclusive scan of deg -> rowptr (+ dinv fused) ----------
__global__ __launch_bounds__(256) void scan_part_kernel(const int* __restrict__ deg,
                                                        int* __restrict__ part) {
    __shared__ int s[256];
    int t = threadIdx.x, i = blockIdx.x * 256 + t;
    s[t] = (i < NN) ? deg[i] : 0;
    __syncthreads();
    for (int off = 128; off > 0; off >>= 1) {
        if (t < off) s[t] += s[t + off];
        __syncthreads();
    }
    if (t == 0) part[blockIdx.x] = s[0];
}

__global__ __launch_bounds__(256) void scan_mid_kernel(int* __restrict__ part,
                                                       int* __restrict__ rowptr) {
    __shared__ int s[256];
    int t = threadIdx.x;
    int v = (t < NBLK) ? part[t] : 0;
    s[t] = v;
    __syncthreads();
    for (int off = 1; off < 256; off <<= 1) {
        int u = (t >= off) ? s[t - off] : 0;
        __syncthreads();
        s[t] += u;
        __syncthreads();
    }
    if (t < NBLK) part[t] = s[t] - v;        // exclusive block offsets
    if (t == 255) rowptr[NN] = s[255];       // total edge count
}

__global__ __launch_bounds__(256) void scan_write_kernel(const int* __restrict__ deg,
                                                         const int* __restrict__ part,
                                                         int* __restrict__ rowptr,
                                                         float* __restrict__ dinv) {
    __shared__ int s[256];
    int t = threadIdx.x, i = blockIdx.x * 256 + t;
    int v = (i < NN) ? deg[i] : 0;
    s[t] = v;
    __syncthreads();
    for (int off = 1; off < 256; off <<= 1) {
        int u = (t >= off) ? s[t - off] : 0;
        __syncthreads();
        s[t] += u;
        __syncthreads();
    }
    if (i < NN) {
        rowptr[i] = part[blockIdx.x] + s[t] - v;
        dinv[i] = 1.0f / sqrtf((float)v + 1.0f);   // +1 = self-loop
    }
}

// scatter edge ids into CSR slots; weight precomputed
__global__ void fill_kernel(const void* ei, const int* __restrict__ flag,
                            const int* __restrict__ rowptr, int* cursor,
                            const float* __restrict__ dinv,
                            int* __restrict__ srcs, float* __restrict__ wts) {
    int e = blockIdx.x * 256 + threadIdx.x;
    if (e >= NE) return;
    int is64 = *flag;
    int s, d; load_edge(ei, e, is64, s, d);
    if ((unsigned)s >= NN || (unsigned)d >= NN) return;
    int slot = rowptr[d] + atomicAdd(&cursor[d], 1);
    srcs[slot] = s;
    wts[slot] = dinv[s] * dinv[d];
}

// ---------- GEMM: T[M x 128] = A[M x 128] @ W[128 x 128] ----------
// 64-row tile, 128 threads (2 waves). Thread = 8 rows (ty+8j) x 8 cols
// (tx*4 and 64+tx*4). A staged full-K in LDS (stride 132, b128-aligned,
// conflict-free reads); W read from GLOBAL (L1-resident, VMEM pipe) so the
// per-CU LDS pipe only carries A traffic: 8 b128 / 4k-step = 96 cyc vs
// VALU 128 cyc -> VALU-bound.
__global__ __launch_bounds__(128, 4) void gemm128_kernel(const float* __restrict__ A,
                                                         const float* __restrict__ W,
                                                         float* __restrict__ T) {
    __shared__ float sA[64 * 132];    // 33 KB
    int tid = threadIdx.x;
    int ty = tid >> 4, tx = tid & 15;     // ty 0..7, tx 0..15
    int m0 = blockIdx.x * 64;
    // stage A tile: 64 rows x 128 cols = 2048 float4, 16 per thread
#pragma unroll
    for (int i = 0; i < 16; ++i) {
        int idx = tid + i * 128;          // 0..2047
        int row = idx >> 5;               // 0..63
        int c4 = idx & 31;                // 0..31
        int grow = m0 + row;
        float4 v = make_float4(0, 0, 0, 0);
        if (grow < NN) v = *(const float4*)(A + (size_t)grow * D + c4 * 4);
        *(float4*)&sA[row * 132 + c4 * 4] = v;
    }
    __syncthreads();
    float4 acc[8][2];
#pragma unroll
    for (int j = 0; j < 8; ++j) {
        acc[j][0] = make_float4(0, 0, 0, 0);
        acc[j][1] = make_float4(0, 0, 0, 0);
    }
#pragma unroll 2
    for (int kk = 0; kk < D; kk += 4) {
        float4 av[8];
#pragma unroll
        for (int j = 0; j < 8; ++j)
            av[j] = *(const float4*)&sA[(ty + 8 * j) * 132 + kk];
#pragma unroll
        for (int t = 0; t < 4; ++t) {
            const float4* wrow = (const float4*)(W + (size_t)(kk + t) * D);
            float4 w0 = wrow[tx], w1 = wrow[tx + 16];
#pragma unroll
            for (int j = 0; j < 8; ++j) {
                float a = ((const float*)&av[j])[t];
                acc[j][0].x = fmaf(a, w0.x, acc[j][0].x);
                acc[j][0].y = fmaf(a, w0.y, acc[j][0].y);
                acc[j][0].z = fmaf(a, w0.z, acc[j][0].z);
                acc[j][0].w = fmaf(a, w0.w, acc[j][0].w);
                acc[j][1].x = fmaf(a, w1.x, acc[j][1].x);
                acc[j][1].y = fmaf(a, w1.y, acc[j][1].y);
                acc[j][1].z = fmaf(a, w1.z, acc[j][1].z);
                acc[j][1].w = fmaf(a, w1.w, acc[j][1].w);
            }
        }
    }
#pragma unroll
    for (int j = 0; j < 8; ++j) {
        int grow = m0 + ty + 8 * j;
        if (grow < NN) {
            float4* O = (float4*)(T + (size_t)grow * D);
            O[tx] = acc[j][0];
            O[tx + 16] = acc[j][1];
        }
    }
}

// ---------- CSR pull: out[d] = relu( sum_in(T[s]*w) + T[d]*dinv^2 + b ) ----------
// one 64-lane wave per dst node; two 32-lane halves process edge pairs
// (float4 per lane = full 512B row per half); shfl_xor(32) combines halves.
__global__ __launch_bounds__(256) void aggregate_kernel(const float* __restrict__ T,
                                                        const int* __restrict__ rowptr,
                                                        const int* __restrict__ srcs,
                                                        const float* __restrict__ wts,
                                                        const float* __restrict__ dinv,
                                                        const float* __restrict__ b,
                                                        float* __restrict__ out) {
    int wid = (blockIdx.x * 256 + threadIdx.x) >> 6;
    int lane = threadIdx.x & 63;
    int h = lane >> 5, l = lane & 31;
    if (wid >= NN) return;
    float di = dinv[wid];
    float wself = h ? 0.0f : di * di;
    float4 acc = ((const float4*)(T + (size_t)wid * D))[l];
    acc.x *= wself; acc.y *= wself; acc.z *= wself; acc.w *= wself;
    int beg = rowptr[wid], end = rowptr[wid + 1];
    int e = beg;
    for (; e + 7 < end; e += 8) {
        int e0 = e + h, e1 = e + 2 + h, e2 = e + 4 + h, e3 = e + 6 + h;
        int s0 = srcs[e0], s1 = srcs[e1], s2 = srcs[e2], s3 = srcs[e3];
        float w0 = wts[e0], w1 = wts[e1], w2 = wts[e2], w3 = wts[e3];
        float4 v0 = ((const float4*)(T + (size_t)s0 * D))[l];
        float4 v1 = ((const float4*)(T + (size_t)s1 * D))[l];
        float4 v2 = ((const float4*)(T + (size_t)s2 * D))[l];
        float4 v3 = ((const float4*)(T + (size_t)s3 * D))[l];
        acc.x = fmaf(v0.x, w0, acc.x); acc.y = fmaf(v0.y, w0, acc.y);
        acc.z = fmaf(v0.z, w0, acc.z); acc.w = fmaf(v0.w, w0, acc.w);
        acc.x = fmaf(v1.x, w1, acc.x); acc.y = fmaf(v1.y, w1, acc.y);
        acc.z = fmaf(v1.z, w1, acc.z); acc.w = fmaf(v1.w, w1, acc.w);
        acc.x = fmaf(v2.x, w2, acc.x); acc.y = fmaf(v2.y, w2, acc.y);
        acc.z = fmaf(v2.z, w2, acc.z); acc.w = fmaf(v2.w, w2, acc.w);
        acc.x = fmaf(v3.x, w3, acc.x); acc.y = fmaf(v3.y, w3, acc.y);
        acc.z = fmaf(v3.z, w3, acc.z); acc.w = fmaf(v3.w, w3, acc.w);
    }
    for (; e + 1 < end; e += 2) {
        int ee = e + h;
        int s0 = srcs[ee];
        float w0 = wts[ee];
        float4 v0 = ((const float4*)(T + (size_t)s0 * D))[l];
        acc.x = fmaf(v0.x, w0, acc.x); acc.y = fmaf(v0.y, w0, acc.y);
        acc.z = fmaf(v0.z, w0, acc.z); acc.w = fmaf(v0.w, w0, acc.w);
    }
    if (e < end) {                       // one leftover edge; h==1 contributes 0
        int ee = (e + h < end) ? e + h : end - 1;
        float w0 = (e + h < end) ? wts[ee] : 0.0f;
        int s0 = srcs[ee];
        float4 v0 = ((const float4*)(T + (size_t)s0 * D))[l];
        acc.x = fmaf(v0.x, w0, acc.x); acc.y = fmaf(v0.y, w0, acc.y);
        acc.z = fmaf(v0.z, w0, acc.z); acc.w = fmaf(v0.w, w0, acc.w);
    }
    acc.x += __shfl_xor(acc.x, 32);
    acc.y += __shfl_xor(acc.y, 32);
    acc.z += __shfl_xor(acc.z, 32);
    acc.w += __shfl_xor(acc.w, 32);
    if (h == 0) {
        float4 bb = ((const float4*)b)[l];
        acc.x = fmaxf(acc.x + bb.x, 0.0f);
        acc.y = fmaxf(acc.y + bb.y, 0.0f);
        acc.z = fmaxf(acc.z + bb.z, 0.0f);
        acc.w = fmaxf(acc.w + bb.w, 0.0f);
        ((float4*)(out + (size_t)wid * D))[l] = acc;
    }
}

// O[M x 40] = A[M x 128] @ W[128 x 40] + b
__global__ __launch_bounds__(256) void fc_kernel(const float* __restrict__ A,
                                                 const float* __restrict__ W,
                                                 const float* __restrict__ b,
                                                 float* __restrict__ O) {
    __shared__ float sW[D * NC];
    __shared__ float sH[64 * D];
    int tid = threadIdx.x;
    for (int i = tid; i < D * NC; i += 256) sW[i] = W[i];
    int m0 = blockIdx.x * 64;
#pragma unroll
    for (int i = 0; i < 32; ++i) {
        int idx = tid + i * 256;
        int row = idx >> 7, col = idx & 127;
        int grow = m0 + row;
        float v = (grow < NN) ? A[(size_t)grow * D + col] : 0.0f;
        sH[row * D + (col ^ ((row & 7) << 2))] = v;
    }
    __syncthreads();
    int r = tid >> 2, c0 = (tid & 3) * 10;
    int sw = (r & 7) << 2;
    float acc[10];
#pragma unroll
    for (int j = 0; j < 10; ++j) acc[j] = 0.0f;
    for (int k = 0; k < D; ++k) {
        float a = sH[r * D + (k ^ sw)];
#pragma unroll
        for (int j = 0; j < 10; ++j) acc[j] = fmaf(a, sW[k * NC + c0 + j], acc[j]);
    }
    int grow = m0 + r;
    if (grow < NN) {
#pragma unroll
        for (int j = 0; j < 10; ++j) O[(size_t)grow * NC + c0 + j] = acc[j] + b[c0 + j];
    }
}

extern "C" void kernel_launch(void* const* d_in, const int* in_sizes, int n_in,
                              void* d_out, int out_size, void* d_ws, size_t ws_size,
                              hipStream_t stream) {
    const float* x   = (const float*)d_in[0];
    const void*  ei  = d_in[1];
    const float* W1  = (const float*)d_in[2];
    const float* b1  = (const float*)d_in[3];
    const float* W2  = (const float*)d_in[4];
    const float* b2  = (const float*)d_in[5];
    const float* W3  = (const float*)d_in[6];
    const float* b3  = (const float*)d_in[7];
    const float* fcW = (const float*)d_in[8];
    const float* fcb = (const float*)d_in[9];

    float* out_h  = (float*)d_out;                       // [NN x 128]
    float* out_fc = out_h + (size_t)NN * D;              // [NN x 40]

    size_t off = 0;
    auto alloc = [&](size_t bytes) {
        void* p = (char*)d_ws + off;
        off += (bytes + 255) & ~(size_t)255;
        return p;
    };
    float* dinv   = (float*)alloc((size_t)NN * 4);
    int*   deg    = (int*)  alloc((size_t)NN * 4);
    int*   flag   = (int*)  alloc(256);
    int*   part   = (int*)  alloc((size_t)NBLK * 4);
    int*   rowptr = (int*)  alloc((size_t)(NN + 1) * 4);
    int*   cursor = (int*)  alloc((size_t)NN * 4);
    int*   srcs   = (int*)  alloc((size_t)NE * 4);
    float* wts    = (float*)alloc((size_t)NE * 4);
    float* bufT   = (float*)alloc((size_t)NN * D * 4);
    float* bufH   = (float*)alloc((size_t)NN * D * 4);
    (void)ws_size; (void)in_sizes; (void)n_in; (void)out_size;

    hipMemsetAsync(deg, 0, (size_t)NN * 4, stream);
    hipMemsetAsync(cursor, 0, (size_t)NN * 4, stream);
    detect_kernel<<<1, 256, 0, stream>>>((const int*)ei, flag);
    count_deg_kernel<<<(NE + 255) / 256, 256, 0, stream>>>(ei, flag, deg);
    scan_part_kernel<<<NBLK, 256, 0, stream>>>(deg, part);
    scan_mid_kernel<<<1, 256, 0, stream>>>(part, rowptr);
    scan_write_kernel<<<NBLK, 256, 0, stream>>>(deg, part, rowptr, dinv);
    fill_kernel<<<(NE + 255) / 256, 256, 0, stream>>>(ei, flag, rowptr, cursor, dinv, srcs, wts);

    auto layer = [&](const float* in, const float* W, const float* b, float* out) {
        gemm128_kernel<<<(NN + 63) / 64, 128, 0, stream>>>(in, W, bufT);
        aggregate_kernel<<<(NN * 64 + 255) / 256, 256, 0, stream>>>(bufT, rowptr, srcs, wts, dinv, b, out);
    };

    layer(x,    W1, b1, bufH);
    layer(bufH, W2, b2, bufH);   // aggregate reads only bufT; overwrite of bufH is safe
    layer(bufH, W3, b3, out_h);

    fc_kernel<<<(NN + 63) / 64, 256, 0, stream>>>(out_h, fcW, fcb, out_fc);
}